// Round 3
// baseline (395.279 us; speedup 1.0000x reference)
//
#include <hip/hip_runtime.h>
#include <stdint.h>

#define S_LEN 2048
#define D_MODELX 768
#define N_HEADS 12
#define HEAD_D 64
#define BATCHX 4
#define M_ROWS (BATCHX * S_LEN)  // 8192

typedef __attribute__((ext_vector_type(8))) short bf16x8;
typedef __attribute__((ext_vector_type(4))) short s16x4;
typedef __attribute__((ext_vector_type(4))) float f32x4;

__device__ __forceinline__ short bf16_rne(float f) {
  uint32_t u = __builtin_bit_cast(uint32_t, f);
  u += 0x7FFFu + ((u >> 16) & 1u);
  return (short)(u >> 16);
}

__device__ __forceinline__ void gload_lds16(const void* g, void* l) {
  __builtin_amdgcn_global_load_lds((const __attribute__((address_space(1))) void*)g,
                                   (__attribute__((address_space(3))) void*)l, 16, 0, 0);
}

// ---------------- fused fp32 -> bf16 convert (X + 4 weight matrices) ----------------
__global__ __launch_bounds__(256) void convert_all(
    const float4* __restrict__ X,
    const float4* __restrict__ Wq, const float4* __restrict__ Wk,
    const float4* __restrict__ Wv, const float4* __restrict__ Wy,
    s16x4* __restrict__ Xb,
    s16x4* __restrict__ Wqb, s16x4* __restrict__ Wkb,
    s16x4* __restrict__ Wvb, s16x4* __restrict__ Wyb)
{
  const int NX = M_ROWS * D_MODELX / 4;   // 1572864
  const int NW = D_MODELX * D_MODELX / 4; // 147456
  const int NT = NX + 4 * NW;
  const int stride = gridDim.x * blockDim.x;
  for (int i = blockIdx.x * blockDim.x + threadIdx.x; i < NT; i += stride) {
    const float4* src; s16x4* dst; int off;
    if (i < NX)               { src = X;  dst = Xb;  off = i; }
    else if (i < NX + NW)     { src = Wq; dst = Wqb; off = i - NX; }
    else if (i < NX + 2*NW)   { src = Wk; dst = Wkb; off = i - NX - NW; }
    else if (i < NX + 3*NW)   { src = Wv; dst = Wvb; off = i - NX - 2*NW; }
    else                      { src = Wy; dst = Wyb; off = i - NX - 3*NW; }
    float4 v = src[off];
    s16x4 o;
    o.x = bf16_rne(v.x); o.y = bf16_rne(v.y); o.z = bf16_rne(v.z); o.w = bf16_rne(v.w);
    dst[off] = o;
  }
}

// ---------------- bf16 GEMM:  Out[M,N] = A[M,K] @ W[N,K]^T + bias  ----------------
// 128x128 tile, BK=32, 4 waves (2x2), 16x16x32 MFMA, global_load_lds staging, dbuf.
template<bool OUTF32>
__global__ __launch_bounds__(256) void gemm_kernel(
    const short* __restrict__ A,
    const short* __restrict__ W0, const short* __restrict__ W1, const short* __restrict__ W2,
    const float* __restrict__ b0, const float* __restrict__ b1, const float* __restrict__ b2,
    void* __restrict__ O0, void* __restrict__ O1, void* __restrict__ O2,
    float scale0)
{
  const int K = D_MODELX, N = D_MODELX;
  const int z = blockIdx.z;
  const short* W    = (z == 0) ? W0 : ((z == 1) ? W1 : W2);
  const float* bias = (z == 0) ? b0 : ((z == 1) ? b1 : b2);
  void* Op          = (z == 0) ? O0 : ((z == 1) ? O1 : O2);
  const float scale = (z == 0) ? scale0 : 1.0f;

  const int tid = threadIdx.x;
  const int lane = tid & 63;
  const int wv = tid >> 6;
  const int wm = wv >> 1, wn = wv & 1;
  const int r = lane & 15, g = lane >> 4;

  const int m0 = blockIdx.x * 128;
  const int n0 = blockIdx.y * 128;

  __shared__ short As[2][128 * 32];
  __shared__ short Bs[2][128 * 32];

  const f32x4 fzero = {0.f, 0.f, 0.f, 0.f};
  f32x4 acc[4][4];
  #pragma unroll
  for (int i = 0; i < 4; ++i)
    #pragma unroll
    for (int j = 0; j < 4; ++j) acc[i][j] = fzero;

  const int row_s = lane >> 2;        // row within 16-row chunk
  const int colb  = (lane & 3) * 16;  // byte col within 64B row

  auto stage = [&](int buf, int kt) {
    const int kc = kt * 32;
    #pragma unroll
    for (int it = 0; it < 2; ++it) {
      int chunk = wv * 2 + it;  // 0..7 ; each chunk = 16 rows x 64B
      int row = chunk * 16 + row_s;
      const char* gA = (const char*)(A + (size_t)(m0 + row) * K + kc) + colb;
      const char* gB = (const char*)(W + (size_t)(n0 + row) * K + kc) + colb;
      gload_lds16(gA, (char*)(&As[buf][0]) + chunk * 1024);
      gload_lds16(gB, (char*)(&Bs[buf][0]) + chunk * 1024);
    }
  };

  const int NTK = K / 32;  // 24
  stage(0, 0);
  asm volatile("s_waitcnt vmcnt(0)");
  __syncthreads();

  int cur = 0;
  for (int kt = 0; kt < NTK; ++kt) {
    if (kt + 1 < NTK) stage(cur ^ 1, kt + 1);
    bf16x8 af[4], bfr[4];
    #pragma unroll
    for (int i = 0; i < 4; ++i)
      af[i] = *(const bf16x8*)(&As[cur][(wm * 64 + i * 16 + r) * 32 + g * 8]);
    #pragma unroll
    for (int j = 0; j < 4; ++j)
      bfr[j] = *(const bf16x8*)(&Bs[cur][(wn * 64 + j * 16 + r) * 32 + g * 8]);
    #pragma unroll
    for (int i = 0; i < 4; ++i)
      #pragma unroll
      for (int j = 0; j < 4; ++j)
        acc[i][j] = __builtin_amdgcn_mfma_f32_16x16x32_bf16(af[i], bfr[j], acc[i][j], 0, 0, 0);
    asm volatile("s_waitcnt vmcnt(0)");
    __syncthreads();
    cur ^= 1;
  }

  #pragma unroll
  for (int j = 0; j < 4; ++j) {
    const int col = n0 + wn * 64 + j * 16 + r;
    const float bv_ = bias[col];
    #pragma unroll
    for (int i = 0; i < 4; ++i) {
      const int rowb = m0 + wm * 64 + i * 16 + g * 4;
      #pragma unroll
      for (int e = 0; e < 4; ++e) {
        float v = (acc[i][j][e] + bv_) * scale;
        if (OUTF32) ((float*)Op)[(size_t)(rowb + e) * N + col] = v;
        else        ((short*)Op)[(size_t)(rowb + e) * N + col] = bf16_rne(v);
      }
    }
  }
}

// ---------------- flash attention: per (b,h), QBLK=64 (16 rows/wave), KVBLK=64 ----------------
// Q pre-scaled by 0.125 in projection. Scores C-layout: row=q=(g*4+i), col=kv=r.
__global__ __launch_bounds__(256) void attn_kernel(
    const short* __restrict__ Q, const short* __restrict__ K,
    const short* __restrict__ V, const int* __restrict__ mask,
    short* __restrict__ O)
{
  const int b = blockIdx.z, h = blockIdx.y;
  const int tid = threadIdx.x;
  const int lane = tid & 63, wv = tid >> 6;
  const int r = lane & 15, g = lane >> 4;
  const int q0 = blockIdx.x * 64 + wv * 16;
  const size_t hb = (size_t)b * S_LEN * D_MODELX + h * HEAD_D;

  // V^T in LDS, row stride 72 shorts (144B, 16B-aligned), kv-chunk XOR-swizzled by (d>>3):
  // offset16(d,kv) = d*72 + (((kv>>3) ^ (d>>3))<<3) + (kv&7)  -> conflict-free writes, ~2-way reads
  __shared__ short Vt[64 * 72];
  __shared__ short Pb[4][16 * 72];  // per-wave P (16 q x 64 kv), pad-72 rows

  bf16x8 qf[2];
  #pragma unroll
  for (int f = 0; f < 2; ++f)
    qf[f] = *(const bf16x8*)(Q + hb + (size_t)(q0 + r) * D_MODELX + f * 32 + g * 8);

  const f32x4 fzero = {0.f, 0.f, 0.f, 0.f};
  f32x4 o[4];
  #pragma unroll
  for (int j = 0; j < 4; ++j) o[j] = fzero;
  float mr[4] = {-1e30f, -1e30f, -1e30f, -1e30f};
  float lr[4] = {0.f, 0.f, 0.f, 0.f};

  int voff[2][4];  // LDS short-offsets for V B-frags, kv0-independent
  #pragma unroll
  for (int h2 = 0; h2 < 2; ++h2)
    #pragma unroll
    for (int dn = 0; dn < 4; ++dn) {
      int d = dn * 16 + r;
      int kv = h2 * 32 + g * 8;
      voff[h2][dn] = d * 72 + (((kv >> 3) ^ (d >> 3)) << 3);
    }

  const int* mrow = mask + (size_t)b * S_LEN;
  short* pb = &Pb[wv][0];

  for (int kv0 = 0; kv0 < S_LEN; kv0 += 64) {
    __syncthreads();  // previous iteration's Vt reads done
    // stage V tile transposed+swizzled: coalesced global reads (8 rows x 128B per wave instr)
    #pragma unroll
    for (int c = 0; c < 2; ++c) {
      int id = tid + 256 * c;      // 0..511
      int kvr = id >> 3;           // 0..63
      int c8 = (id & 7) * 8;       // d-chunk base
      bf16x8 vvv = *(const bf16x8*)(V + hb + (size_t)(kv0 + kvr) * D_MODELX + c8);
      #pragma unroll
      for (int j = 0; j < 8; ++j) {
        int d = c8 + j;
        Vt[d * 72 + (((kvr >> 3) ^ (d >> 3)) << 3) + (kvr & 7)] = vvv[j];
      }
    }
    __syncthreads();

    // QK^T: 4 col-tiles of 16, K-frags straight from global (L2-resident)
    f32x4 s[4];
    #pragma unroll
    for (int nt = 0; nt < 4; ++nt) {
      const short* krow = K + hb + (size_t)(kv0 + nt * 16 + r) * D_MODELX;
      bf16x8 kf0 = *(const bf16x8*)(krow + g * 8);
      bf16x8 kf1 = *(const bf16x8*)(krow + 32 + g * 8);
      f32x4 t = fzero;
      t = __builtin_amdgcn_mfma_f32_16x16x32_bf16(qf[0], kf0, t, 0, 0, 0);
      t = __builtin_amdgcn_mfma_f32_16x16x32_bf16(qf[1], kf1, t, 0, 0, 0);
      int mk = mrow[kv0 + nt * 16 + r];
      if (mk == 0) { t[0] = -1e30f; t[1] = -1e30f; t[2] = -1e30f; t[3] = -1e30f; }
      s[nt] = t;
    }

    // online softmax (per q-row; row stats live in all 16 lanes of the row's group)
    #pragma unroll
    for (int i = 0; i < 4; ++i) {
      float bm = fmaxf(fmaxf(s[0][i], s[1][i]), fmaxf(s[2][i], s[3][i]));
      bm = fmaxf(bm, __shfl_xor(bm, 1));
      bm = fmaxf(bm, __shfl_xor(bm, 2));
      bm = fmaxf(bm, __shfl_xor(bm, 4));
      bm = fmaxf(bm, __shfl_xor(bm, 8));
      float mnew = fmaxf(mr[i], bm);
      float alpha = __expf(mr[i] - mnew);
      mr[i] = mnew;
      #pragma unroll
      for (int dn = 0; dn < 4; ++dn) o[dn][i] *= alpha;
      float rs = 0.f;
      #pragma unroll
      for (int nt = 0; nt < 4; ++nt) {
        float p = __expf(s[nt][i] - mnew);
        s[nt][i] = p;
        rs += p;
      }
      rs += __shfl_xor(rs, 1);
      rs += __shfl_xor(rs, 2);
      rs += __shfl_xor(rs, 4);
      rs += __shfl_xor(rs, 8);
      lr[i] = lr[i] * alpha + rs;
    }

    // P -> LDS (C-layout write, conflict-free), read back as A-frags
    #pragma unroll
    for (int nt = 0; nt < 4; ++nt)
      #pragma unroll
      for (int i = 0; i < 4; ++i)
        pb[(g * 4 + i) * 72 + nt * 16 + r] = bf16_rne(s[nt][i]);

    bf16x8 pa[2];
    #pragma unroll
    for (int h2 = 0; h2 < 2; ++h2)
      pa[h2] = *(const bf16x8*)(pb + r * 72 + h2 * 32 + g * 8);

    // PV: o[dn] += P(16xkv) @ V(kv x 16d)
    #pragma unroll
    for (int h2 = 0; h2 < 2; ++h2)
      #pragma unroll
      for (int dn = 0; dn < 4; ++dn) {
        bf16x8 vf = *(const bf16x8*)(&Vt[voff[h2][dn]]);
        o[dn] = __builtin_amdgcn_mfma_f32_16x16x32_bf16(pa[h2], vf, o[dn], 0, 0, 0);
      }
  }

  #pragma unroll
  for (int i = 0; i < 4; ++i) {
    float inv = 1.0f / lr[i];
    #pragma unroll
    for (int dn = 0; dn < 4; ++dn) o[dn][i] *= inv;
  }
  #pragma unroll
  for (int dn = 0; dn < 4; ++dn)
    #pragma unroll
    for (int i = 0; i < 4; ++i)
      O[hb + (size_t)(q0 + g * 4 + i) * D_MODELX + dn * 16 + r] = bf16_rne(o[dn][i]);
}

// ---------------- host launch ----------------
extern "C" void kernel_launch(void* const* d_in, const int* in_sizes, int n_in,
                              void* d_out, int out_size, void* d_ws, size_t ws_size,
                              hipStream_t stream)
{
  const float* hs = (const float*)d_in[0];
  const int* mask = (const int*)d_in[1];
  const float* Wq = (const float*)d_in[2];
  const float* bq = (const float*)d_in[3];
  const float* Wk = (const float*)d_in[4];
  const float* bk = (const float*)d_in[5];
  const float* Wv = (const float*)d_in[6];
  const float* bv = (const float*)d_in[7];
  const float* Wy = (const float*)d_in[8];
  const float* by = (const float*)d_in[9];

  char* ws = (char*)d_ws;
  const size_t SZ_X = (size_t)M_ROWS * D_MODELX * 2;    // 12.6 MB
  const size_t SZ_W = (size_t)D_MODELX * D_MODELX * 2;  // 1.18 MB
  short* Xb  = (short*)(ws);
  short* Wqb = (short*)(ws + SZ_X);
  short* Wkb = (short*)(ws + SZ_X + SZ_W);
  short* Wvb = (short*)(ws + SZ_X + 2 * SZ_W);
  short* Wyb = (short*)(ws + SZ_X + 3 * SZ_W);
  short* Qb  = (short*)(ws + SZ_X + 4 * SZ_W);
  short* Kb  = (short*)(ws + 2 * SZ_X + 4 * SZ_W);
  short* Vb  = (short*)(ws + 3 * SZ_X + 4 * SZ_W);
  short* Ab  = Xb;  // alias: Xb is dead after QKV GEMM; stream serializes kernels

  convert_all<<<2048, 256, 0, stream>>>(
      (const float4*)hs, (const float4*)Wq, (const float4*)Wk, (const float4*)Wv, (const float4*)Wy,
      (s16x4*)Xb, (s16x4*)Wqb, (s16x4*)Wkb, (s16x4*)Wvb, (s16x4*)Wyb);

  // fused QKV projections; Q pre-scaled by 1/sqrt(64)
  gemm_kernel<false><<<dim3(M_ROWS / 128, D_MODELX / 128, 3), 256, 0, stream>>>(
      Xb, Wqb, Wkb, Wvb, bq, bk, bv, (void*)Qb, (void*)Kb, (void*)Vb, 0.125f);

  attn_kernel<<<dim3(S_LEN / 64, N_HEADS, BATCHX), 256, 0, stream>>>(Qb, Kb, Vb, mask, Ab);

  // output projection -> fp32 d_out
  gemm_kernel<true><<<dim3(M_ROWS / 128, D_MODELX / 128, 1), 256, 0, stream>>>(
      Ab, Wyb, Wyb, Wyb, by, by, by, d_out, d_out, d_out, 1.0f);
}